// Round 4
// baseline (3267.896 us; speedup 1.0000x reference)
//
#include <hip/hip_runtime.h>
#include <cstdint>

typedef _Float16 f16x8 __attribute__((ext_vector_type(8)));
typedef float    f32x4 __attribute__((ext_vector_type(4)));

#define BB 64
#define TT 256
#define EE 512
#define UU 1024
#define NN 3072   // 3*U

// ---------------- prep: Wh -> f16 MFMA B-fragment layout ----------------
// WhF[((j*3+g)*32 + kb)*64 + lane][jj] = f16(Wh[kb*32 + quad*8 + jj][g*1024 + j*16 + l16])
__global__ __launch_bounds__(256) void prep_whf(const float* __restrict__ Wh,
                                                _Float16* __restrict__ WhF) {
    int tid  = blockIdx.x * 256 + threadIdx.x;   // 0..393215
    int col8 = tid % 384;
    int k    = tid / 384;                        // 0..1023
    int kb = k >> 5, quad = (k >> 3) & 3, jj = k & 7;
    const float* src = Wh + (long)k * NN + col8 * 8;
#pragma unroll
    for (int i = 0; i < 8; i++) {
        int n   = col8 * 8 + i;
        int g   = n >> 10;
        int nl  = n & 1023;
        int j   = nl >> 4, l16 = nl & 15;
        int lane = quad * 16 + l16;
        WhF[((((j * 3 + g) * 32 + kb) * 64 + lane) << 3) + jj] = (_Float16)src[i];
    }
}

// ---------------- prep: Wx -> f16 MFMA B-fragment layout (fast proj path) ----
// WxF[((n16*16 + kb)*64 + lane)*8 + jj] = f16(Wx[kb*32 + quad*8 + jj][n16*16 + l16])
__global__ __launch_bounds__(256) void prep_wxf(const float* __restrict__ Wx,
                                                _Float16* __restrict__ WxF) {
    int tid  = blockIdx.x * 256 + threadIdx.x;   // 0..196607
    int col8 = tid % 384;
    int k    = tid / 384;                        // 0..511
    int kb = k >> 5, quad = (k >> 3) & 3, jj = k & 7;
    const float* src = Wx + (long)k * NN + col8 * 8;
#pragma unroll
    for (int i = 0; i < 8; i++) {
        int n   = col8 * 8 + i;
        int n16 = n >> 4, l16 = n & 15;
        int lane = quad * 16 + l16;
        WxF[(((n16 * 16 + kb) * 64 + lane) << 3) + jj] = (_Float16)src[i];
    }
}

__global__ __launch_bounds__(256) void prep_h0(const float* __restrict__ h0,
                                               _Float16* __restrict__ hbuf) {
    int i = blockIdx.x * 256 + threadIdx.x;      // 0..65535
    hbuf[i] = (_Float16)h0[i];
}

// ---------------- embed + input projection GEMM, fast path (pre-packed WxF) ----
__global__ __launch_bounds__(256) void proj_fast(
    const int* __restrict__ tokens, const float* __restrict__ emb,
    const _Float16* __restrict__ WxF, const float* __restrict__ bx,
    _Float16* __restrict__ xproj) {
    int tid  = threadIdx.x;
    int wave = tid >> 6, lane = tid & 63, quad = lane >> 4, l16 = lane & 15;
    int bm = blockIdx.x * 64;
    int bn = blockIdx.y * 128;
    int wm = (wave & 1) * 32, wn = (wave >> 1) * 64;

    int row0 = bm + wm + l16;
    const float* a0p = emb + (long)tokens[row0] * EE;
    const float* a1p = emb + (long)tokens[row0 + 16] * EE;

    f32x4 acc[2][4];
#pragma unroll
    for (int mt = 0; mt < 2; mt++)
#pragma unroll
        for (int nt = 0; nt < 4; nt++) { f32x4 z = {0.f, 0.f, 0.f, 0.f}; acc[mt][nt] = z; }

    int n16base = (bn + wn) >> 4;
#pragma unroll 2
    for (int k0 = 0; k0 < EE; k0 += 32) {
        int kb = k0 >> 5;
        int ka = k0 + quad * 8;
        f16x8 afr[2];
        {
            const float4* p = (const float4*)(a0p + ka);
            float4 x0 = p[0], x1 = p[1];
            afr[0][0] = (_Float16)x0.x; afr[0][1] = (_Float16)x0.y;
            afr[0][2] = (_Float16)x0.z; afr[0][3] = (_Float16)x0.w;
            afr[0][4] = (_Float16)x1.x; afr[0][5] = (_Float16)x1.y;
            afr[0][6] = (_Float16)x1.z; afr[0][7] = (_Float16)x1.w;
        }
        {
            const float4* p = (const float4*)(a1p + ka);
            float4 x0 = p[0], x1 = p[1];
            afr[1][0] = (_Float16)x0.x; afr[1][1] = (_Float16)x0.y;
            afr[1][2] = (_Float16)x0.z; afr[1][3] = (_Float16)x0.w;
            afr[1][4] = (_Float16)x1.x; afr[1][5] = (_Float16)x1.y;
            afr[1][6] = (_Float16)x1.z; afr[1][7] = (_Float16)x1.w;
        }
        f16x8 bfr[4];
#pragma unroll
        for (int nt = 0; nt < 4; nt++)
            bfr[nt] = *((const f16x8*)WxF + (((n16base + nt) * 16 + kb) * 64 + lane));
#pragma unroll
        for (int mt = 0; mt < 2; mt++)
#pragma unroll
            for (int nt = 0; nt < 4; nt++)
                acc[mt][nt] = __builtin_amdgcn_mfma_f32_16x16x32_f16(afr[mt], bfr[nt], acc[mt][nt], 0, 0, 0);
    }
#pragma unroll
    for (int mt = 0; mt < 2; mt++) {
        int rowbase = bm + wm + mt * 16 + quad * 4;
#pragma unroll
        for (int nt = 0; nt < 4; nt++) {
            int col = bn + wn + nt * 16 + l16;
            float bias = bx[col];
#pragma unroll
            for (int r = 0; r < 4; r++) {
                int i = rowbase + r;
                int b = i >> 8, t = i & 255;
                xproj[((long)t * BB + b) * NN + col] = (_Float16)(acc[mt][nt][r] + bias);
            }
        }
    }
}

// ---------------- embed + input projection GEMM, fallback (strided Wx) ----
__global__ __launch_bounds__(256) void proj_kernel(
    const int* __restrict__ tokens, const float* __restrict__ emb,
    const float* __restrict__ Wx, const float* __restrict__ bx,
    _Float16* __restrict__ xproj) {
    int tid  = threadIdx.x;
    int wave = tid >> 6, lane = tid & 63, quad = lane >> 4, l16 = lane & 15;
    int bm = blockIdx.x * 64;
    int bn = blockIdx.y * 128;
    int wm = (wave & 1) * 32, wn = (wave >> 1) * 64;

    int row0 = bm + wm + l16;
    const float* a0p = emb + (long)tokens[row0] * EE;
    const float* a1p = emb + (long)tokens[row0 + 16] * EE;

    f32x4 acc[2][4];
#pragma unroll
    for (int mt = 0; mt < 2; mt++)
#pragma unroll
        for (int nt = 0; nt < 4; nt++) { f32x4 z = {0.f, 0.f, 0.f, 0.f}; acc[mt][nt] = z; }

#pragma unroll 2
    for (int k0 = 0; k0 < EE; k0 += 32) {
        int ka = k0 + quad * 8;
        f16x8 afr[2];
        {
            const float4* p = (const float4*)(a0p + ka);
            float4 x0 = p[0], x1 = p[1];
            afr[0][0] = (_Float16)x0.x; afr[0][1] = (_Float16)x0.y;
            afr[0][2] = (_Float16)x0.z; afr[0][3] = (_Float16)x0.w;
            afr[0][4] = (_Float16)x1.x; afr[0][5] = (_Float16)x1.y;
            afr[0][6] = (_Float16)x1.z; afr[0][7] = (_Float16)x1.w;
        }
        {
            const float4* p = (const float4*)(a1p + ka);
            float4 x0 = p[0], x1 = p[1];
            afr[1][0] = (_Float16)x0.x; afr[1][1] = (_Float16)x0.y;
            afr[1][2] = (_Float16)x0.z; afr[1][3] = (_Float16)x0.w;
            afr[1][4] = (_Float16)x1.x; afr[1][5] = (_Float16)x1.y;
            afr[1][6] = (_Float16)x1.z; afr[1][7] = (_Float16)x1.w;
        }
        f16x8 bfr[4];
#pragma unroll
        for (int nt = 0; nt < 4; nt++) {
            const float* bp = Wx + (long)ka * NN + (bn + wn + nt * 16 + l16);
#pragma unroll
            for (int jj = 0; jj < 8; jj++) bfr[nt][jj] = (_Float16)bp[(long)jj * NN];
        }
#pragma unroll
        for (int mt = 0; mt < 2; mt++)
#pragma unroll
            for (int nt = 0; nt < 4; nt++)
                acc[mt][nt] = __builtin_amdgcn_mfma_f32_16x16x32_f16(afr[mt], bfr[nt], acc[mt][nt], 0, 0, 0);
    }
#pragma unroll
    for (int mt = 0; mt < 2; mt++) {
        int rowbase = bm + wm + mt * 16 + quad * 4;
#pragma unroll
        for (int nt = 0; nt < 4; nt++) {
            int col = bn + wn + nt * 16 + l16;
            float bias = bx[col];
#pragma unroll
            for (int r = 0; r < 4; r++) {
                int i = rowbase + r;
                int b = i >> 8, t = i & 255;
                xproj[((long)t * BB + b) * NN + col] = (_Float16)(acc[mt][nt][r] + bias);
            }
        }
    }
}

// ---------------- persistent GRU recurrence ----------------
// 64 WGs (1/CU), WG j owns u-slice [16j,16j+16). Weights register-pinned (R2).
// R3 KEY CHANGE: decentralized barrier. Per-WG flag release-STORE (write-through
// to IC, no RMW line-bouncing), wave0's 64 lanes poll all 64 flags in parallel
// with relaxed loads + ballot. All loop stores (h slice, out) are nontemporal
// so L2 stays clean and the release fence's wbl2 has nothing to drain.
// out-stores + next-step xproj prefetch overlap with the poll.
__global__ __launch_bounds__(256, 1) void gru_kernel(
    const _Float16* __restrict__ xproj,   // [T][B][3U]
    const _Float16* __restrict__ WhF,     // fragment layout
    const float* __restrict__ hidden,     // [B][U] fp32 h0
    const float* __restrict__ bh,         // [3U]
    _Float16* __restrict__ hbuf,          // [2][B][U]
    unsigned int* flags,                  // [64]
    float* __restrict__ out) {            // [B][T][U] ++ [B][U]
    int tid  = threadIdx.x;
    int wave = tid >> 6, lane = tid & 63, quad = lane >> 4, l16 = lane & 15;
    int j  = blockIdx.x;
    int u  = j * 16 + l16;
    int b0 = wave * 16;

    float bhz = bh[u], bhr = bh[UU + u], bhh = bh[2 * UU + u];

    float hold[4];
#pragma unroll
    for (int r = 0; r < 4; r++) hold[r] = hidden[(long)(b0 + quad * 4 + r) * UU + u];

    // prefetch x_proj for t=0
    float xzv[4], xrv[4], xhv[4];
#pragma unroll
    for (int r = 0; r < 4; r++) {
        const _Float16* p = xproj + (long)(b0 + quad * 4 + r) * NN + u;
        xzv[r] = (float)p[0]; xrv[r] = (float)p[UU]; xhv[r] = (float)p[2 * UU];
    }

    // ---- load the whole per-WG weight slice into registers, ONCE ----
    const f16x8* WF = (const f16x8*)WhF + (long)j * 3 * 32 * 64 + lane;
    f16x8 w[96];                      // w[g*32+kb]
#pragma unroll
    for (int i = 0; i < 96; i++) w[i] = WF[(long)i * 64];
#pragma unroll
    for (int i = 0; i < 60; i++) asm volatile("" : "+a"(w[i]));
#pragma unroll
    for (int i = 60; i < 96; i++) asm volatile("" : "+v"(w[i]));

#pragma unroll 1
    for (int t = 0; t < TT; t++) {
        const _Float16* h = hbuf + (long)(t & 1) * BB * UU + (long)(b0 + l16) * UU + quad * 8;
        f32x4 az = {0.f, 0.f, 0.f, 0.f}, ar = az, ah = az;
#pragma unroll
        for (int kb = 0; kb < 32; kb++) {
            f16x8 afr = *(const f16x8*)(h + kb * 32);
            az = __builtin_amdgcn_mfma_f32_16x16x32_f16(afr, w[kb],      az, 0, 0, 0);
            ar = __builtin_amdgcn_mfma_f32_16x16x32_f16(afr, w[32 + kb], ar, 0, 0, 0);
            ah = __builtin_amdgcn_mfma_f32_16x16x32_f16(afr, w[64 + kb], ah, 0, 0, 0);
        }

#pragma unroll
        for (int r = 0; r < 4; r++) {
            float z  = 1.f / (1.f + expf(-(xzv[r] + az[r] + bhz)));
            float rr = 1.f / (1.f + expf(-(xrv[r] + ar[r] + bhr)));
            float cd = tanhf(xhv[r] + rr * (ah[r] + bhh));
            hold[r] = z * hold[r] + (1.f - z) * cd;
        }

        if (t != TT - 1) {
            // publish h slice (nontemporal -> write-through, L2 stays clean)
            _Float16* hw = hbuf + (long)((t + 1) & 1) * BB * UU;
#pragma unroll
            for (int r = 0; r < 4; r++)
                __builtin_nontemporal_store((_Float16)hold[r],
                    hw + (long)(b0 + quad * 4 + r) * UU + u);
            __syncthreads();   // drains vmcnt: all this WG's h stores visible
            if (tid == 0)
                __hip_atomic_store(&flags[j], (unsigned)(t + 1),
                                   __ATOMIC_RELEASE, __HIP_MEMORY_SCOPE_AGENT);
            // overlap with the poll: out stores + next-step xproj prefetch
#pragma unroll
            for (int r = 0; r < 4; r++) {
                int b = b0 + quad * 4 + r;
                __builtin_nontemporal_store(hold[r],
                    out + (long)b * TT * UU + (long)t * UU + u);
            }
            {
                const _Float16* p2 = xproj + (long)(t + 1) * BB * NN;
#pragma unroll
                for (int r = 0; r < 4; r++) {
                    const _Float16* p = p2 + (long)(b0 + quad * 4 + r) * NN + u;
                    xzv[r] = (float)p[0]; xrv[r] = (float)p[UU]; xhv[r] = (float)p[2 * UU];
                }
            }
            if (wave == 0) {
                unsigned tgt = (unsigned)(t + 1);
                unsigned v = __hip_atomic_load(&flags[lane], __ATOMIC_RELAXED,
                                               __HIP_MEMORY_SCOPE_AGENT);
                while (__ballot(v < tgt) != 0ull) {
                    __builtin_amdgcn_s_sleep(1);
                    v = __hip_atomic_load(&flags[lane], __ATOMIC_RELAXED,
                                          __HIP_MEMORY_SCOPE_AGENT);
                }
                __builtin_amdgcn_fence(__ATOMIC_ACQUIRE, "agent");
            }
            __syncthreads();
        } else {
#pragma unroll
            for (int r = 0; r < 4; r++) {
                int b = b0 + quad * 4 + r;
                __builtin_nontemporal_store(hold[r],
                    out + (long)b * TT * UU + (long)t * UU + u);
                out[(long)BB * TT * UU + (long)b * UU + u] = hold[r];
            }
        }
    }
}

// ---------------- launch ----------------
extern "C" void kernel_launch(void* const* d_in, const int* in_sizes, int n_in,
                              void* d_out, int out_size, void* d_ws, size_t ws_size,
                              hipStream_t stream) {
    const int*   tokens = (const int*)d_in[0];
    const float* hidden = (const float*)d_in[1];
    const float* emb    = (const float*)d_in[2];
    const float* Wx     = (const float*)d_in[3];
    const float* bx     = (const float*)d_in[4];
    const float* Wh     = (const float*)d_in[5];
    const float* bh     = (const float*)d_in[6];
    float* out = (float*)d_out;

    char* ws = (char*)d_ws;
    _Float16* xproj = (_Float16*)(ws);                  // 100663296 B
    _Float16* WhF   = (_Float16*)(ws + 100663296L);     //   6291456 B
    _Float16* hbuf  = (_Float16*)(ws + 106954752L);     //    262144 B
    unsigned* flags = (unsigned*)(ws + 107216896L);     //       256 B (64 flags)
    _Float16* WxF   = (_Float16*)(ws + 107217152L);     //   3145728 B (fast path only)
    if (ws_size < 107217152UL) return;

    hipMemsetAsync(flags, 0, 256, stream);
    prep_whf<<<1536, 256, 0, stream>>>(Wh, WhF);
    prep_h0<<<256, 256, 0, stream>>>(hidden, hbuf);
    if (ws_size >= 110362880UL) {
        prep_wxf<<<768, 256, 0, stream>>>(Wx, WxF);
        proj_fast<<<dim3(256, 24), 256, 0, stream>>>(tokens, emb, WxF, bx, xproj);
    } else {
        proj_kernel<<<dim3(256, 24), 256, 0, stream>>>(tokens, emb, Wx, bx, xproj);
    }
    gru_kernel<<<64, 256, 0, stream>>>(xproj, WhF, hidden, bh, hbuf, flags, out);
}